// Round 5
// baseline (4157.721 us; speedup 1.0000x reference)
//
#include <hip/hip_runtime.h>
#include <cmath>

// Fixed problem structure (from setup_inputs): T=50 nodes/tree, K=4 branching.
// local parent lp(i) = (i-1)/4; depths: {0},[1,5),[5,21),[21,50)
// parents (nodes with children): locals 0..12 -> compact "parent layout" rows tree*13+local
// Trees are independent -> chunk over trees so workspace fits ANY ws_size.
// Per-tree ws floats: h(50*512) + c(50*512) + xf(13*512) + hsum + fcsum + F(29*512) = 86016
#define T_NODES 50
#define NPARL   13
#define DIN     384
#define HID     512

#define BM 64
#define BN 64
#define BK 32

__device__ __forceinline__ float sigf(float x) { return 1.0f / (1.0f + expf(-x)); }

// MODE 0: iou update -> h,c  (NG=3). WITHC adds h_sum@U_iou (K-concat) + fc_sum in epilogue.
// MODE 1: store acc+bias to compact parent-layout out (NG=1)   [xf = embed@W_f + b_f]
// MODE 2: F: sigmoid(acc + xf[parent]) * c[node] -> compact child-layout out (NG=1)
// All row indices are chunk-local: row r -> tree = r/lspan, local = l0 + r%lspan.
template<int NG, int MODE, bool WITHC>
__global__ __launch_bounds__(256)
void gemm_tree(const float* __restrict__ A1, int lda1, int K1,
               const float* __restrict__ A2,   // h_sum, compact parent layout (WITHC)
               const float* __restrict__ B1,   // K1 x (NG*HID) row-major
               const float* __restrict__ B2,   // HID x (NG*HID) row-major (WITHC)
               const float* __restrict__ bias,
               const float* __restrict__ xf,   // MODE 2
               const float* __restrict__ cin,  // MODE 2
               const float* __restrict__ fcs,  // MODE 0 + WITHC
               float* __restrict__ out1,
               float* __restrict__ out2,
               int M, int l0, int lspan)
{
    const int ldb = NG * HID;
    __shared__ float As[BK][BM + 4];
    __shared__ float Bs[NG][BK][BN];

    const int tid  = threadIdx.x;
    const int row0 = blockIdx.x * BM;
    const int nc0  = blockIdx.y * BN;

    // ---- per-thread A-load row mapping (2 rows: lrow, lrow+32) ----
    const int lrow = tid >> 3;          // 0..31
    const int lk4  = (tid & 7) << 2;    // 0..28 step 4
    const float* rp1[2];
    const float* rp2[2];
    bool rv[2];
    #pragma unroll
    for (int p = 0; p < 2; ++p) {
        int r = row0 + lrow + p * 32;
        rv[p] = (r < M);
        int rr = rv[p] ? r : 0;
        int tree  = rr / lspan;
        int local = l0 + (rr - tree * lspan);
        rp1[p] = A1 + (size_t)(tree * T_NODES + local) * lda1;
        rp2[p] = WITHC ? (A2 + (size_t)(tree * NPARL + local) * HID) : nullptr;
    }

    float acc[NG][4][4];
    #pragma unroll
    for (int g = 0; g < NG; ++g)
        #pragma unroll
        for (int i = 0; i < 4; ++i)
            #pragma unroll
            for (int j = 0; j < 4; ++j) acc[g][i][j] = 0.f;

    const int KT = K1 + (WITHC ? HID : 0);
    for (int k0 = 0; k0 < KT; k0 += BK) {
        const bool seg2 = WITHC && (k0 >= K1);
        // ---- stage A tile (BMxBK), stored transposed As[k][m] ----
        #pragma unroll
        for (int p = 0; p < 2; ++p) {
            float4 v = make_float4(0.f, 0.f, 0.f, 0.f);
            if (rv[p]) {
                const float* rp = seg2 ? (rp2[p] + (k0 - K1)) : (rp1[p] + k0);
                v = *(const float4*)(rp + lk4);
            }
            As[lk4 + 0][lrow + p * 32] = v.x;
            As[lk4 + 1][lrow + p * 32] = v.y;
            As[lk4 + 2][lrow + p * 32] = v.z;
            As[lk4 + 3][lrow + p * 32] = v.w;
        }
        // ---- stage B tiles (NG x BK x BN) ----
        {
            const float* Bsrc = seg2 ? B2 : B1;
            const int kb = seg2 ? (k0 - K1) : k0;
            const int kr = tid >> 3;            // 0..31
            #pragma unroll
            for (int g = 0; g < NG; ++g) {
                #pragma unroll
                for (int q = 0; q < 2; ++q) {
                    int n = ((tid & 7) << 2) + q * 32;
                    float4 v = *(const float4*)(Bsrc + (size_t)(kb + kr) * ldb + g * HID + nc0 + n);
                    *(float4*)&Bs[g][kr][n] = v;
                }
            }
        }
        __syncthreads();
        // ---- compute: 16x16 threads, 4x4 micro-tile, NG gates ----
        {
            const int ty = tid >> 4, tx = tid & 15;
            #pragma unroll
            for (int k = 0; k < BK; ++k) {
                float4 a4 = *(const float4*)&As[k][ty << 2];
                float av[4] = {a4.x, a4.y, a4.z, a4.w};
                #pragma unroll
                for (int g = 0; g < NG; ++g) {
                    float4 b4 = *(const float4*)&Bs[g][k][tx << 2];
                    float bv[4] = {b4.x, b4.y, b4.z, b4.w};
                    #pragma unroll
                    for (int i = 0; i < 4; ++i)
                        #pragma unroll
                        for (int j = 0; j < 4; ++j)
                            acc[g][i][j] += av[i] * bv[j];
                }
            }
        }
        __syncthreads();
    }

    // ---- epilogue ----
    const int ty = tid >> 4, tx = tid & 15;
    #pragma unroll
    for (int i = 0; i < 4; ++i) {
        int r = row0 + (ty << 2) + i;
        if (r >= M) continue;
        int tree  = r / lspan;
        int local = l0 + (r - tree * lspan);
        size_t grow = (size_t)(tree * T_NODES + local);
        int col = nc0 + (tx << 2);
        if constexpr (MODE == 0) {
            size_t crow = (size_t)(tree * NPARL + local);
            float hv[4], cv[4];
            #pragma unroll
            for (int j = 0; j < 4; ++j) {
                int hcol = col + j;
                float pi = acc[0][i][j] + bias[hcol];
                float po = acc[1][i][j] + bias[HID + hcol];
                float pu = acc[2][i][j] + bias[2 * HID + hcol];
                float cc = sigf(pi) * tanhf(pu);
                if (WITHC) cc += fcs[crow * HID + hcol];
                float hh = sigf(po) * tanhf(cc);
                cv[j] = cc; hv[j] = hh;
            }
            *(float4*)&out1[grow * HID + col] = make_float4(hv[0], hv[1], hv[2], hv[3]);
            *(float4*)&out2[grow * HID + col] = make_float4(cv[0], cv[1], cv[2], cv[3]);
        } else if constexpr (MODE == 1) {
            size_t crow = (size_t)(tree * NPARL + local);
            float v[4];
            #pragma unroll
            for (int j = 0; j < 4; ++j) v[j] = acc[0][i][j] + bias[col + j];
            *(float4*)&out1[crow * HID + col] = make_float4(v[0], v[1], v[2], v[3]);
        } else {
            int lp = (local - 1) >> 2;
            size_t prow = (size_t)(tree * NPARL + lp);
            float4 xv = *(const float4*)&xf[prow * HID + col];
            float4 cc = *(const float4*)&cin[grow * HID + col];
            float xvp[4] = {xv.x, xv.y, xv.z, xv.w};
            float cvp[4] = {cc.x, cc.y, cc.z, cc.w};
            float ov[4];
            #pragma unroll
            for (int j = 0; j < 4; ++j)
                ov[j] = sigf(acc[0][i][j] + xvp[j]) * cvp[j];
            *(float4*)&out1[(size_t)r * HID + col] = make_float4(ov[0], ov[1], ov[2], ov[3]);
        }
    }
}

// 4:1 sibling reduction: h_sum / fc_sum per parent (compact parent layout)
__global__ void reduce_kernel(const float* __restrict__ h,
                              const float* __restrict__ F,
                              float* __restrict__ hsum,
                              float* __restrict__ fcsum,
                              int Mp, int p0, int pspan, int c0, int cspan)
{
    int idx = blockIdx.x * blockDim.x + threadIdx.x;
    int total = Mp * (HID / 4);
    if (idx >= total) return;
    int pr  = idx / (HID / 4);
    int col = (idx - pr * (HID / 4)) * 4;
    int tree = pr / pspan;
    int j = p0 + (pr - tree * pspan);
    float hs[4] = {0,0,0,0}, fs[4] = {0,0,0,0};
    #pragma unroll
    for (int s = 0; s < 4; ++s) {
        int cl = 4 * j + 1 + s;
        if (cl < T_NODES) {
            float4 hv = *(const float4*)&h[(size_t)(tree * T_NODES + cl) * HID + col];
            float4 fv = *(const float4*)&F[(size_t)(tree * cspan + (cl - c0)) * HID + col];
            hs[0] += hv.x; hs[1] += hv.y; hs[2] += hv.z; hs[3] += hv.w;
            fs[0] += fv.x; fs[1] += fv.y; fs[2] += fv.z; fs[3] += fv.w;
        }
    }
    size_t prow = (size_t)(tree * NPARL + j);
    *(float4*)&hsum[prow * HID + col]  = make_float4(hs[0], hs[1], hs[2], hs[3]);
    *(float4*)&fcsum[prow * HID + col] = make_float4(fs[0], fs[1], fs[2], fs[3]);
}

// per-graph sum over 50 nodes; split into mu (cols 0..255) and tanh(logvar) (cols 256..511)
// h is chunk-local; g0 is the chunk's first global tree id; B is total trees.
__global__ void readout_kernel(const float* __restrict__ h, float* __restrict__ out,
                               int bc, int g0, int B)
{
    int idx = blockIdx.x * blockDim.x + threadIdx.x;
    if (idx >= bc * HID) return;
    int g = idx / HID;
    int col = idx - g * HID;
    float s = 0.f;
    #pragma unroll 10
    for (int t = 0; t < T_NODES; ++t)
        s += h[(size_t)(g * T_NODES + t) * HID + col];
    int gg = g0 + g;
    if (col < 256) out[(size_t)gg * 256 + col] = s;
    else           out[(size_t)B * 256 + (size_t)gg * 256 + (col - 256)] = tanhf(s);
}

extern "C" void kernel_launch(void* const* d_in, const int* in_sizes, int n_in,
                              void* d_out, int out_size, void* d_ws, size_t ws_size,
                              hipStream_t stream)
{
    const float* embed = (const float*)d_in[0];
    const float* W_iou = (const float*)d_in[1];
    const float* U_iou = (const float*)d_in[2];
    const float* b_iou = (const float*)d_in[3];
    const float* W_f   = (const float*)d_in[4];
    const float* U_f   = (const float*)d_in[5];
    const float* b_f   = (const float*)d_in[6];

    const int N = in_sizes[0] / DIN;   // 100000
    const int B = N / T_NODES;         // 2000

    // ---- choose tree-chunk size from ws_size (per-tree: 86016 floats = 344064 B) ----
    const size_t PER_TREE = 86016;                       // floats
    size_t ws_floats = ws_size / sizeof(float);
    int Bc = (int)(ws_floats / PER_TREE);
    if (Bc > 500) Bc = 500;                              // 172 MB cap; robustness > ~3% launch overhead
    if (Bc > B)   Bc = B;
    if (Bc < 1)   Bc = 1;                                // degenerate; ws must hold >= 344 KB

    // chunk workspace layout (floats), fixed by Bc:
    float* ws    = (float*)d_ws;
    float* h     = ws;                                   // Bc*50*512
    float* c     = h     + (size_t)Bc * T_NODES * HID;   // Bc*50*512
    float* xf    = c     + (size_t)Bc * T_NODES * HID;   // Bc*13*512
    float* hsum  = xf    + (size_t)Bc * NPARL * HID;
    float* fcsum = hsum  + (size_t)Bc * NPARL * HID;
    float* Fws   = fcsum + (size_t)Bc * NPARL * HID;     // Bc*29*512

    dim3 blk(256);
    auto grd = [](int M) { return dim3((unsigned)((M + BM - 1) / BM), HID / BN); };

    // Levels deep->root: children range, parent range, update range (locals)
    struct Lvl { int c0, cspan, p0, pspan, u0, uspan; };
    const Lvl L[3] = {
        {21, 29, 5, 8, 5, 8},   // lvl 2: children 21..49, parents/update 5..12
        { 5, 16, 1, 4, 1, 4},   // lvl 1: children 5..20,  parents/update 1..4
        { 1,  4, 0, 1, 0, 1},   // lvl 0: children 1..4,   parent/update 0
    };

    for (int g0 = 0; g0 < B; g0 += Bc) {
        const int bc = (B - g0 < Bc) ? (B - g0) : Bc;
        const float* embed_c = embed + (size_t)g0 * T_NODES * DIN;

        // Phase 0a: leaf update (zero child sums) for locals [13,50)
        {
            int M = bc * 37;
            hipLaunchKernelGGL((gemm_tree<3, 0, false>), grd(M), blk, 0, stream,
                embed_c, DIN, DIN, (const float*)nullptr, W_iou, (const float*)nullptr,
                b_iou, (const float*)nullptr, (const float*)nullptr, (const float*)nullptr,
                h, c, M, 13, 37);
        }
        // Phase 0b: xf = embed@W_f + b_f for parent locals [0,13)
        {
            int M = bc * NPARL;
            hipLaunchKernelGGL((gemm_tree<1, 1, false>), grd(M), blk, 0, stream,
                embed_c, DIN, DIN, (const float*)nullptr, W_f, (const float*)nullptr,
                b_f, (const float*)nullptr, (const float*)nullptr, (const float*)nullptr,
                xf, (float*)nullptr, M, 0, NPARL);
        }
        for (int li = 0; li < 3; ++li) {
            const Lvl& v = L[li];
            int Mc = bc * v.cspan;
            hipLaunchKernelGGL((gemm_tree<1, 2, false>), grd(Mc), blk, 0, stream,
                h, HID, HID, (const float*)nullptr, U_f, (const float*)nullptr,
                (const float*)nullptr, xf, c, (const float*)nullptr,
                Fws, (float*)nullptr, Mc, v.c0, v.cspan);
            int Mp = bc * v.pspan;
            int tot = Mp * (HID / 4);
            hipLaunchKernelGGL(reduce_kernel, dim3((tot + 255) / 256), blk, 0, stream,
                h, Fws, hsum, fcsum, Mp, v.p0, v.pspan, v.c0, v.cspan);
            int Mu = bc * v.uspan;
            hipLaunchKernelGGL((gemm_tree<3, 0, true>), grd(Mu), blk, 0, stream,
                embed_c, DIN, DIN, hsum, W_iou, U_iou, b_iou,
                (const float*)nullptr, (const float*)nullptr, fcsum,
                h, c, Mu, v.u0, v.uspan);
        }
        // Readout for this chunk
        {
            int tot = bc * HID;
            hipLaunchKernelGGL(readout_kernel, dim3((tot + 255) / 256), blk, 0, stream,
                h, (float*)d_out, bc, g0, B);
        }
    }
}

// Round 6
// 2523.811 us; speedup vs baseline: 1.6474x; 1.6474x over previous
//
#include <hip/hip_runtime.h>
#include <cmath>

// TreeLSTM, fixed topology: T=50 nodes/tree, K=4 branching.
// local parent lp(i)=(i-1)/4; level ranges {0},[1,5),[5,21),[21,50); parents = locals 0..12.
// Trees independent -> chunk over trees to fit any ws_size.
// GEMMs run on fp16 MFMA (16x16x32, fp32 accum); weights pre-transposed+converted to fp16 once.
#define T_NODES 50
#define NPARL   13
#define DIN     384
#define HID     512
#define BK      32      // K per step
#define PADK    40      // LDS row pitch in halfs (80B = 20-bank stride, conflict-free b128 frags)
#define BMR     128     // rows per block

typedef _Float16 half8 __attribute__((ext_vector_type(8)));
typedef float    f32x4 __attribute__((ext_vector_type(4)));

__device__ __forceinline__ float sigf(float x) { return 1.0f / (1.0f + expf(-x)); }

// out[c*K + k] = (fp16) in[k*NCOL + c]   (transpose + convert; runs once per call, small)
__global__ void transpose_cvt(const float* __restrict__ in, _Float16* __restrict__ out,
                              int K, int NCOL)
{
    int idx = blockIdx.x * blockDim.x + threadIdx.x;
    if (idx >= K * NCOL) return;
    int c = idx / K, k = idx - c * K;
    out[(size_t)c * K + k] = (_Float16)in[(size_t)k * NCOL + c];
}

// MFMA GEMM over tree-mapped rows. Row r -> tree=r/lspan, local=l0+r%lspan.
// A1: fp32, row stride KB1 (embed: 384, h: 512), rows at tree*T_NODES+local.
// A2 (WITHC): fp32 hsum, parent-compact rows tree*NPARL+local, stride HID (K-concat segment).
// B1t/B2t: fp16 pre-transposed weights [outcol][k], row stride KB1 / HID.
// MODE 0: iou -> h,c (NG=3; block covers BN h-cols x 3 gates). WITHC adds hsum@U_iou + fc_sum.
// MODE 1: acc+bias -> parent-compact out (NG=1).
// MODE 2: sigmoid(acc + xf[parent]) * c[node] -> child-span out (NG=1).
template<int NG, int MODE, bool WITHC>
__global__ __launch_bounds__(256)
void gemm_mfma(const float* __restrict__ A1, int KB1,
               const float* __restrict__ A2,
               const _Float16* __restrict__ B1t,
               const _Float16* __restrict__ B2t,
               const float* __restrict__ bias,
               const float* __restrict__ xf,
               const float* __restrict__ cin,
               const float* __restrict__ fcs,
               float* __restrict__ out1,
               float* __restrict__ out2,
               int M, int l0, int lspan)
{
    constexpr int BN  = (NG == 3) ? 64 : 128;   // h-cols per block
    constexpr int BNT = NG * BN;                // LDS B cols (192 or 128)
    constexpr int NTW = BN / 32;                // col 16-tiles per wave per gate (2 or 4)

    __shared__ _Float16 As[BMR][PADK];
    __shared__ _Float16 Bs[BNT][PADK];

    const int tid  = threadIdx.x;
    const int lane = tid & 63;
    const int wid  = tid >> 6;
    const int wr   = wid >> 1;      // wave row half (64 rows each)
    const int wc   = wid & 1;       // wave col half
    const int row0 = blockIdx.y * BMR;
    const int nc0  = blockIdx.x * BN;

    // ---- per-thread A staging row (1 row, 16 k-elems) ----
    const int  arow = tid >> 1;
    const int  koff = (tid & 1) * 16;
    const int  arg  = row0 + arow;
    const bool av   = (arg < M);
    int arr = av ? arg : 0;
    int atree  = arr / lspan;
    int alocal = l0 + (arr - atree * lspan);
    const float* rpa1 = A1 + (size_t)(atree * T_NODES + alocal) * KB1;
    const float* rpa2 = WITHC ? (A2 + (size_t)(atree * NPARL + alocal) * HID) : nullptr;

    f32x4 acc[4][NG][NTW];
    #pragma unroll
    for (int mt = 0; mt < 4; ++mt)
        #pragma unroll
        for (int g = 0; g < NG; ++g)
            #pragma unroll
            for (int nt = 0; nt < NTW; ++nt)
                acc[mt][g][nt] = (f32x4){0.f, 0.f, 0.f, 0.f};

    const int KT = KB1 + (WITHC ? HID : 0);
    for (int k0 = 0; k0 < KT; k0 += BK) {
        const bool seg2 = WITHC && (k0 >= KB1);
        // ---- stage A: fp32 load -> fp16 -> LDS [row][k] ----
        {
            const float* s = seg2 ? (rpa2 + (k0 - KB1) + koff) : (rpa1 + k0 + koff);
            _Float16 tmp[16];
            #pragma unroll
            for (int p = 0; p < 4; ++p) {
                float4 v = av ? *(const float4*)(s + p * 4) : make_float4(0.f, 0.f, 0.f, 0.f);
                tmp[p * 4 + 0] = (_Float16)v.x;
                tmp[p * 4 + 1] = (_Float16)v.y;
                tmp[p * 4 + 2] = (_Float16)v.z;
                tmp[p * 4 + 3] = (_Float16)v.w;
            }
            *(half8*)&As[arow][koff]     = *(half8*)&tmp[0];
            *(half8*)&As[arow][koff + 8] = *(half8*)&tmp[8];
        }
        // ---- stage B: fp16 pre-transposed copy -> LDS [col][k] ----
        {
            const _Float16* Bt = seg2 ? B2t : B1t;
            const int KB = seg2 ? HID : KB1;
            const int kb = seg2 ? (k0 - KB1) : k0;
            #pragma unroll
            for (int i = 0; i < BNT / 64; ++i) {     // BNT*4 b128-chunks / 256 threads
                int chunk = tid + i * 256;
                int col = chunk >> 2, kq = chunk & 3;
                int gcol;
                if constexpr (NG == 3) gcol = (col >> 6) * HID + nc0 + (col & 63);
                else                   gcol = nc0 + col;
                half8 w = *(const half8*)(Bt + (size_t)gcol * KB + kb + kq * 8);
                *(half8*)&Bs[col][kq * 8] = w;
            }
        }
        __syncthreads();
        // ---- fragments + MFMA ----
        {
            const int kch = (lane >> 4) * 8;
            const int afr = wr * 64 + (lane & 15);
            half8 af[4];
            #pragma unroll
            for (int mt = 0; mt < 4; ++mt)
                af[mt] = *(const half8*)&As[afr + mt * 16][kch];
            #pragma unroll
            for (int g = 0; g < NG; ++g)
                #pragma unroll
                for (int nt = 0; nt < NTW; ++nt) {
                    half8 bf = *(const half8*)&Bs[g * BN + wc * (BN / 2) + nt * 16 + (lane & 15)][kch];
                    #pragma unroll
                    for (int mt = 0; mt < 4; ++mt)
                        acc[mt][g][nt] = __builtin_amdgcn_mfma_f32_16x16x32_f16(
                            af[mt], bf, acc[mt][g][nt], 0, 0, 0);
                }
        }
        __syncthreads();
    }

    // ---- epilogue: C tile mapping col=lane&15, row=(lane>>4)*4+r ----
    const int rgrp = (lane >> 4) * 4;
    #pragma unroll
    for (int mt = 0; mt < 4; ++mt) {
        #pragma unroll
        for (int nt = 0; nt < NTW; ++nt) {
            const int col_h = nc0 + wc * (BN / 2) + nt * 16 + (lane & 15);
            #pragma unroll
            for (int r = 0; r < 4; ++r) {
                int rl = row0 + wr * 64 + mt * 16 + rgrp + r;
                if (rl >= M) continue;
                int tree  = rl / lspan;
                int local = l0 + (rl - tree * lspan);
                size_t grow = (size_t)(tree * T_NODES + local);
                if constexpr (MODE == 0) {
                    size_t crow = (size_t)(tree * NPARL + local);
                    float pi = acc[mt][0][nt][r] + bias[col_h];
                    float po = acc[mt][1][nt][r] + bias[HID + col_h];
                    float pu = acc[mt][2][nt][r] + bias[2 * HID + col_h];
                    float cc = sigf(pi) * tanhf(pu);
                    if (WITHC) cc += fcs[crow * HID + col_h];
                    float hh = sigf(po) * tanhf(cc);
                    out1[grow * HID + col_h] = hh;
                    out2[grow * HID + col_h] = cc;
                } else if constexpr (MODE == 1) {
                    size_t crow = (size_t)(tree * NPARL + local);
                    out1[crow * HID + col_h] = acc[mt][0][nt][r] + bias[col_h];
                } else {
                    int lp = (local - 1) >> 2;
                    size_t prow = (size_t)(tree * NPARL + lp);
                    float f = sigf(acc[mt][0][nt][r] + xf[prow * HID + col_h]);
                    out1[(size_t)rl * HID + col_h] = f * cin[grow * HID + col_h];
                }
            }
        }
    }
}

// 4:1 sibling reduction: h_sum / fc_sum per parent (compact parent layout)
__global__ void reduce_kernel(const float* __restrict__ h,
                              const float* __restrict__ F,
                              float* __restrict__ hsum,
                              float* __restrict__ fcsum,
                              int Mp, int p0, int pspan, int c0, int cspan)
{
    int idx = blockIdx.x * blockDim.x + threadIdx.x;
    int total = Mp * (HID / 4);
    if (idx >= total) return;
    int pr  = idx / (HID / 4);
    int col = (idx - pr * (HID / 4)) * 4;
    int tree = pr / pspan;
    int j = p0 + (pr - tree * pspan);
    float hs[4] = {0,0,0,0}, fs[4] = {0,0,0,0};
    #pragma unroll
    for (int s = 0; s < 4; ++s) {
        int cl = 4 * j + 1 + s;
        if (cl < T_NODES) {
            float4 hv = *(const float4*)&h[(size_t)(tree * T_NODES + cl) * HID + col];
            float4 fv = *(const float4*)&F[(size_t)(tree * cspan + (cl - c0)) * HID + col];
            hs[0] += hv.x; hs[1] += hv.y; hs[2] += hv.z; hs[3] += hv.w;
            fs[0] += fv.x; fs[1] += fv.y; fs[2] += fv.z; fs[3] += fv.w;
        }
    }
    size_t prow = (size_t)(tree * NPARL + j);
    *(float4*)&hsum[prow * HID + col]  = make_float4(hs[0], hs[1], hs[2], hs[3]);
    *(float4*)&fcsum[prow * HID + col] = make_float4(fs[0], fs[1], fs[2], fs[3]);
}

// per-graph sum over 50 nodes; split into mu and tanh(logvar)
__global__ void readout_kernel(const float* __restrict__ h, float* __restrict__ out,
                               int bc, int g0, int B)
{
    int idx = blockIdx.x * blockDim.x + threadIdx.x;
    if (idx >= bc * HID) return;
    int g = idx / HID;
    int col = idx - g * HID;
    float s = 0.f;
    #pragma unroll 10
    for (int t = 0; t < T_NODES; ++t)
        s += h[(size_t)(g * T_NODES + t) * HID + col];
    int gg = g0 + g;
    if (col < 256) out[(size_t)gg * 256 + col] = s;
    else           out[(size_t)B * 256 + (size_t)gg * 256 + (col - 256)] = tanhf(s);
}

extern "C" void kernel_launch(void* const* d_in, const int* in_sizes, int n_in,
                              void* d_out, int out_size, void* d_ws, size_t ws_size,
                              hipStream_t stream)
{
    const float* embed = (const float*)d_in[0];
    const float* W_iou = (const float*)d_in[1];
    const float* U_iou = (const float*)d_in[2];
    const float* b_iou = (const float*)d_in[3];
    const float* W_f   = (const float*)d_in[4];
    const float* U_f   = (const float*)d_in[5];
    const float* b_f   = (const float*)d_in[6];

    const int N = in_sizes[0] / DIN;   // 100000
    const int B = N / T_NODES;         // 2000

    // ---- ws carve: fp16 transposed weights first, then per-chunk fp32 buffers ----
    _Float16* Wt_iou = (_Float16*)d_ws;                     // [1536][384]
    _Float16* Ut_iou = Wt_iou + (size_t)3 * HID * DIN;      // [1536][512]
    _Float16* Wt_f   = Ut_iou + (size_t)3 * HID * HID;      // [512][384]
    _Float16* Ut_f   = Wt_f   + (size_t)HID * DIN;          // [512][512]
    const size_t WGT_HALFS = (size_t)3 * HID * DIN + (size_t)3 * HID * HID
                           + (size_t)HID * DIN + (size_t)HID * HID;   // 1,835,008
    const size_t WGT_FLOATS = WGT_HALFS / 2;                 // 917,504 (16B-aligned)

    const size_t PER_TREE = 86016;                           // fp32 scratch floats per tree
    size_t avail = ws_size / sizeof(float);
    avail = (avail > WGT_FLOATS) ? (avail - WGT_FLOATS) : 0;
    int Bc = (int)(avail / PER_TREE);
    if (Bc > B) Bc = B;
    if (Bc < 1) Bc = 1;

    float* fbase = (float*)d_ws + WGT_FLOATS;
    float* h     = fbase;                                    // Bc*50*512
    float* c     = h     + (size_t)Bc * T_NODES * HID;
    float* xf    = c     + (size_t)Bc * T_NODES * HID;       // Bc*13*512
    float* hsum  = xf    + (size_t)Bc * NPARL * HID;
    float* fcsum = hsum  + (size_t)Bc * NPARL * HID;
    float* Fws   = fcsum + (size_t)Bc * NPARL * HID;         // Bc*29*512

    dim3 blk(256);
    // grid: x = col-blocks (A-rows reused across consecutive x -> L2-friendly), y = row-blocks
    auto grd = [](int M, int ng) {
        return dim3((unsigned)(HID / ((ng == 3) ? 64 : 128)), (unsigned)((M + BMR - 1) / BMR));
    };

    // ---- one-time weight transpose+convert (replayed each call; ~20us) ----
    hipLaunchKernelGGL(transpose_cvt, dim3((DIN * 3 * HID + 255) / 256), blk, 0, stream,
                       W_iou, Wt_iou, DIN, 3 * HID);
    hipLaunchKernelGGL(transpose_cvt, dim3((HID * 3 * HID + 255) / 256), blk, 0, stream,
                       U_iou, Ut_iou, HID, 3 * HID);
    hipLaunchKernelGGL(transpose_cvt, dim3((DIN * HID + 255) / 256), blk, 0, stream,
                       W_f, Wt_f, DIN, HID);
    hipLaunchKernelGGL(transpose_cvt, dim3((HID * HID + 255) / 256), blk, 0, stream,
                       U_f, Ut_f, HID, HID);

    // Levels deep->root: children range, parent range, update range (locals)
    struct Lvl { int c0, cspan, p0, pspan, u0, uspan; };
    const Lvl L[3] = {
        {21, 29, 5, 8, 5, 8},
        { 5, 16, 1, 4, 1, 4},
        { 1,  4, 0, 1, 0, 1},
    };

    for (int g0 = 0; g0 < B; g0 += Bc) {
        const int bc = (B - g0 < Bc) ? (B - g0) : Bc;
        const float* embed_c = embed + (size_t)g0 * T_NODES * DIN;

        // Phase 0a: leaf update (zero child sums) for locals [13,50)
        {
            int M = bc * 37;
            hipLaunchKernelGGL((gemm_mfma<3, 0, false>), grd(M, 3), blk, 0, stream,
                embed_c, DIN, (const float*)nullptr, Wt_iou, (const _Float16*)nullptr,
                b_iou, (const float*)nullptr, (const float*)nullptr, (const float*)nullptr,
                h, c, M, 13, 37);
        }
        // Phase 0b: xf = embed@W_f + b_f for parent locals [0,13)
        {
            int M = bc * NPARL;
            hipLaunchKernelGGL((gemm_mfma<1, 1, false>), grd(M, 1), blk, 0, stream,
                embed_c, DIN, (const float*)nullptr, Wt_f, (const _Float16*)nullptr,
                b_f, (const float*)nullptr, (const float*)nullptr, (const float*)nullptr,
                xf, (float*)nullptr, M, 0, NPARL);
        }
        for (int li = 0; li < 3; ++li) {
            const Lvl& v = L[li];
            int Mc = bc * v.cspan;
            hipLaunchKernelGGL((gemm_mfma<1, 2, false>), grd(Mc, 1), blk, 0, stream,
                h, HID, (const float*)nullptr, Ut_f, (const _Float16*)nullptr,
                (const float*)nullptr, xf, c, (const float*)nullptr,
                Fws, (float*)nullptr, Mc, v.c0, v.cspan);
            int Mp = bc * v.pspan;
            int tot = Mp * (HID / 4);
            hipLaunchKernelGGL(reduce_kernel, dim3((tot + 255) / 256), blk, 0, stream,
                h, Fws, hsum, fcsum, Mp, v.p0, v.pspan, v.c0, v.cspan);
            int Mu = bc * v.uspan;
            hipLaunchKernelGGL((gemm_mfma<3, 0, true>), grd(Mu, 3), blk, 0, stream,
                embed_c, DIN, hsum, Wt_iou, Ut_iou, b_iou,
                (const float*)nullptr, (const float*)nullptr, fcsum,
                h, c, Mu, v.u0, v.uspan);
        }
        // Readout for this chunk
        {
            int tot = bc * HID;
            hipLaunchKernelGGL(readout_kernel, dim3((tot + 255) / 256), blk, 0, stream,
                h, (float*)d_out, bc, g0, B);
        }
    }
}

// Round 7
// 1545.966 us; speedup vs baseline: 2.6894x; 1.6325x over previous
//
#include <hip/hip_runtime.h>
#include <cmath>

// TreeLSTM, fixed topology: T=50 nodes/tree, K=4 branching.
// local parent lp(i)=(i-1)/4; level ranges {0},[1,5),[5,21),[21,50); parents = locals 0..12.
// Trees independent -> chunk over trees to fit any ws_size.
// All GEMM A-operands materialized fp16 (embed16/h16/hsum16); MFMA 16x16x32 fp32-accum.
// XCD-bijective tile swizzle: all col-blocks of a row-block land on one XCD (A fetched once).
#define T_NODES 50
#define NPARL   13
#define DIN     384
#define HID     512
#define BK      32      // K per step
#define PADK    40      // LDS row pitch in halfs (80B: 16B-aligned rows, <=2-way bank alias)
#define BMR     128     // rows per block

typedef _Float16 half8 __attribute__((ext_vector_type(8)));
typedef _Float16 half4 __attribute__((ext_vector_type(4)));
typedef float    f32x4 __attribute__((ext_vector_type(4)));

__device__ __forceinline__ float sigf(float x) { return 1.0f / (1.0f + expf(-x)); }

// out[c*K + k] = (fp16) in[k*NCOL + c]   (weight transpose+convert; small, once per call)
__global__ void transpose_cvt(const float* __restrict__ in, _Float16* __restrict__ out,
                              int K, int NCOL)
{
    int idx = blockIdx.x * blockDim.x + threadIdx.x;
    if (idx >= K * NCOL) return;
    int c = idx / K, k = idx - c * K;
    out[(size_t)c * K + k] = (_Float16)in[(size_t)k * NCOL + c];
}

// elementwise fp32 -> fp16, 8 elems/thread (n8 = n/8, n divisible by 8)
__global__ void cvt_f32_f16(const float* __restrict__ in, _Float16* __restrict__ out, int n8)
{
    int i = blockIdx.x * blockDim.x + threadIdx.x;
    if (i >= n8) return;
    float4 a = ((const float4*)in)[2 * i];
    float4 b = ((const float4*)in)[2 * i + 1];
    half8 o;
    o[0] = (_Float16)a.x; o[1] = (_Float16)a.y; o[2] = (_Float16)a.z; o[3] = (_Float16)a.w;
    o[4] = (_Float16)b.x; o[5] = (_Float16)b.y; o[6] = (_Float16)b.z; o[7] = (_Float16)b.w;
    ((half8*)out)[i] = o;
}

// MFMA GEMM over tree-mapped rows. Row r -> tree=r/lspan, local=l0+r%lspan.
// A1: fp16, row stride KB1, rows at tree*T_NODES+local (embed16 or h16).
// A2h (WITHC): fp16 hsum16, parent-compact rows tree*NPARL+local (K-concat segment).
// B1t/B2t: fp16 pre-transposed weights [outcol][k].
// MODE 0: iou -> h,c(,h16). WITHC adds hsum@U_iou + fc_sum.
// MODE 1: acc+bias -> parent-compact out (NG=1).
// MODE 2: sigmoid(acc + xf[parent]) * c[node] -> child-span out (NG=1).
template<int NG, int MODE, bool WITHC>
__global__ __launch_bounds__(256)
void gemm_mfma(const _Float16* __restrict__ A1, int KB1,
               const _Float16* __restrict__ A2h,
               const _Float16* __restrict__ B1t,
               const _Float16* __restrict__ B2t,
               const float* __restrict__ bias,
               const float* __restrict__ xf,
               const float* __restrict__ cin,
               const float* __restrict__ fcs,
               float* __restrict__ out1,
               float* __restrict__ out2,
               _Float16* __restrict__ outh,
               int M, int l0, int lspan)
{
    constexpr int BN  = (NG == 3) ? 64 : 128;   // h-cols per block
    constexpr int BNT = NG * BN;                // LDS B cols (192 or 128)
    constexpr int NTW = BN / 32;                // col 16-tiles per wave per gate

    __shared__ _Float16 As[BMR][PADK];
    __shared__ _Float16 Bs[BNT][PADK];

    const int tid  = threadIdx.x;
    const int lane = tid & 63;
    const int wid  = tid >> 6;
    const int wr   = wid >> 1;
    const int wc   = wid & 1;

    // ---- XCD-bijective swizzle: gridDim.y is a multiple of 8 (host-padded).
    // Dispatch order flat = y*nX + x, XCD ~ flat%8 (round-robin heuristic, perf-only).
    // XCD k owns row-blocks [k*q, (k+1)*q), cycling col-blocks -> A-tile read by 1 XCD only.
    const int nX = gridDim.x, nY = gridDim.y;
    int flat = blockIdx.y * nX + blockIdx.x;
    int xcd = flat & 7, j = flat >> 3;
    int q  = nY >> 3;
    int bx = j % nX;
    int by = xcd * q + j / nX;
    const int row0 = by * BMR;
    const int nc0  = bx * BN;
    if (row0 >= M) return;   // padding blocks

    // ---- per-thread A staging row (2 threads/row, 16 halfs = 32B each) ----
    const int  arow = tid >> 1;
    const int  koff = (tid & 1) * 16;
    const int  arg  = row0 + arow;
    const bool av   = (arg < M);
    int arr = av ? arg : 0;
    int atree  = arr / lspan;
    int alocal = l0 + (arr - atree * lspan);
    const _Float16* rp1 = A1 + (size_t)(atree * T_NODES + alocal) * KB1;
    const _Float16* rp2 = WITHC ? (A2h + (size_t)(atree * NPARL + alocal) * HID) : nullptr;

    f32x4 acc[4][NG][NTW];
    #pragma unroll
    for (int mt = 0; mt < 4; ++mt)
        #pragma unroll
        for (int g = 0; g < NG; ++g)
            #pragma unroll
            for (int nt = 0; nt < NTW; ++nt)
                acc[mt][g][nt] = (f32x4){0.f, 0.f, 0.f, 0.f};

    const int KT = KB1 + (WITHC ? HID : 0);
    for (int k0 = 0; k0 < KT; k0 += BK) {
        const bool seg2 = WITHC && (k0 >= KB1);
        // ---- stage A: fp16 copy -> LDS [row][k] ----
        {
            const _Float16* s = seg2 ? (rp2 + (k0 - KB1) + koff) : (rp1 + k0 + koff);
            half8 v0 = {}, v1 = {};
            if (av) { v0 = ((const half8*)s)[0]; v1 = ((const half8*)s)[1]; }
            *(half8*)&As[arow][koff]     = v0;
            *(half8*)&As[arow][koff + 8] = v1;
        }
        // ---- stage B: fp16 pre-transposed copy -> LDS [col][k] ----
        {
            const _Float16* Bt = seg2 ? B2t : B1t;
            const int KB = seg2 ? HID : KB1;
            const int kb = seg2 ? (k0 - KB1) : k0;
            #pragma unroll
            for (int i = 0; i < BNT / 64; ++i) {
                int chunk = tid + i * 256;
                int col = chunk >> 2, kq = chunk & 3;
                int gcol;
                if constexpr (NG == 3) gcol = (col >> 6) * HID + nc0 + (col & 63);
                else                   gcol = nc0 + col;
                half8 w = *(const half8*)(Bt + (size_t)gcol * KB + kb + kq * 8);
                *(half8*)&Bs[col][kq * 8] = w;
            }
        }
        __syncthreads();
        // ---- fragments + MFMA ----
        {
            const int kch = (lane >> 4) * 8;
            const int afr = wr * 64 + (lane & 15);
            half8 af[4];
            #pragma unroll
            for (int mt = 0; mt < 4; ++mt)
                af[mt] = *(const half8*)&As[afr + mt * 16][kch];
            #pragma unroll
            for (int g = 0; g < NG; ++g)
                #pragma unroll
                for (int nt = 0; nt < NTW; ++nt) {
                    half8 bf = *(const half8*)&Bs[g * BN + wc * (BN / 2) + nt * 16 + (lane & 15)][kch];
                    #pragma unroll
                    for (int mt = 0; mt < 4; ++mt)
                        acc[mt][g][nt] = __builtin_amdgcn_mfma_f32_16x16x32_f16(
                            af[mt], bf, acc[mt][g][nt], 0, 0, 0);
                }
        }
        __syncthreads();
    }

    // ---- epilogue: C tile mapping col=lane&15, row=(lane>>4)*4+r ----
    const int rgrp = (lane >> 4) * 4;
    #pragma unroll
    for (int mt = 0; mt < 4; ++mt) {
        #pragma unroll
        for (int nt = 0; nt < NTW; ++nt) {
            const int col_h = nc0 + wc * (BN / 2) + nt * 16 + (lane & 15);
            #pragma unroll
            for (int r = 0; r < 4; ++r) {
                int rl = row0 + wr * 64 + mt * 16 + rgrp + r;
                if (rl >= M) continue;
                int tree  = rl / lspan;
                int local = l0 + (rl - tree * lspan);
                size_t grow = (size_t)(tree * T_NODES + local);
                if constexpr (MODE == 0) {
                    size_t crow = (size_t)(tree * NPARL + local);
                    float pi = acc[mt][0][nt][r] + bias[col_h];
                    float po = acc[mt][1][nt][r] + bias[HID + col_h];
                    float pu = acc[mt][2][nt][r] + bias[2 * HID + col_h];
                    float cc = sigf(pi) * tanhf(pu);
                    if (WITHC) cc += fcs[crow * HID + col_h];
                    float hh = sigf(po) * tanhf(cc);
                    out1[grow * HID + col_h] = hh;
                    out2[grow * HID + col_h] = cc;
                    outh[grow * HID + col_h] = (_Float16)hh;
                } else if constexpr (MODE == 1) {
                    size_t crow = (size_t)(tree * NPARL + local);
                    out1[crow * HID + col_h] = acc[mt][0][nt][r] + bias[col_h];
                } else {
                    int lp = (local - 1) >> 2;
                    size_t prow = (size_t)(tree * NPARL + lp);
                    float f = sigf(acc[mt][0][nt][r] + xf[prow * HID + col_h]);
                    out1[(size_t)rl * HID + col_h] = f * cin[grow * HID + col_h];
                }
            }
        }
    }
}

// 4:1 sibling reduction: hsum16 (fp16, for MFMA A) / fc_sum (fp32) per parent
__global__ void reduce_kernel(const float* __restrict__ h,
                              const float* __restrict__ F,
                              _Float16* __restrict__ hsum16,
                              float* __restrict__ fcsum,
                              int Mp, int p0, int pspan, int c0, int cspan)
{
    int idx = blockIdx.x * blockDim.x + threadIdx.x;
    int total = Mp * (HID / 4);
    if (idx >= total) return;
    int pr  = idx / (HID / 4);
    int col = (idx - pr * (HID / 4)) * 4;
    int tree = pr / pspan;
    int j = p0 + (pr - tree * pspan);
    float hs[4] = {0,0,0,0}, fs[4] = {0,0,0,0};
    #pragma unroll
    for (int s = 0; s < 4; ++s) {
        int cl = 4 * j + 1 + s;
        if (cl < T_NODES) {
            float4 hv = *(const float4*)&h[(size_t)(tree * T_NODES + cl) * HID + col];
            float4 fv = *(const float4*)&F[(size_t)(tree * cspan + (cl - c0)) * HID + col];
            hs[0] += hv.x; hs[1] += hv.y; hs[2] += hv.z; hs[3] += hv.w;
            fs[0] += fv.x; fs[1] += fv.y; fs[2] += fv.z; fs[3] += fv.w;
        }
    }
    size_t prow = (size_t)(tree * NPARL + j);
    half4 h16v;
    h16v[0] = (_Float16)hs[0]; h16v[1] = (_Float16)hs[1];
    h16v[2] = (_Float16)hs[2]; h16v[3] = (_Float16)hs[3];
    *(half4*)&hsum16[prow * HID + col] = h16v;
    *(float4*)&fcsum[prow * HID + col] = make_float4(fs[0], fs[1], fs[2], fs[3]);
}

// per-graph sum over 50 nodes; split into mu and tanh(logvar)
__global__ void readout_kernel(const float* __restrict__ h, float* __restrict__ out,
                               int bc, int g0, int B)
{
    int idx = blockIdx.x * blockDim.x + threadIdx.x;
    if (idx >= bc * HID) return;
    int g = idx / HID;
    int col = idx - g * HID;
    float s = 0.f;
    #pragma unroll 10
    for (int t = 0; t < T_NODES; ++t)
        s += h[(size_t)(g * T_NODES + t) * HID + col];
    int gg = g0 + g;
    if (col < 256) out[(size_t)gg * 256 + col] = s;
    else           out[(size_t)B * 256 + (size_t)gg * 256 + (col - 256)] = tanhf(s);
}

extern "C" void kernel_launch(void* const* d_in, const int* in_sizes, int n_in,
                              void* d_out, int out_size, void* d_ws, size_t ws_size,
                              hipStream_t stream)
{
    const float* embed = (const float*)d_in[0];
    const float* W_iou = (const float*)d_in[1];
    const float* U_iou = (const float*)d_in[2];
    const float* b_iou = (const float*)d_in[3];
    const float* W_f   = (const float*)d_in[4];
    const float* U_f   = (const float*)d_in[5];
    const float* b_f   = (const float*)d_in[6];

    const int N = in_sizes[0] / DIN;   // 100000
    const int B = N / T_NODES;         // 2000

    // ---- ws carve: fp16 transposed weights, then per-chunk buffers ----
    _Float16* Wt_iou = (_Float16*)d_ws;                     // [1536][384]
    _Float16* Ut_iou = Wt_iou + (size_t)3 * HID * DIN;      // [1536][512]
    _Float16* Wt_f   = Ut_iou + (size_t)3 * HID * HID;      // [512][384]
    _Float16* Ut_f   = Wt_f   + (size_t)HID * DIN;          // [512][512]
    const size_t WGT_FLOATS = ((size_t)3 * HID * DIN + (size_t)3 * HID * HID
                             + (size_t)HID * DIN + (size_t)HID * HID) / 2;  // 917504

    // per-tree floats: h,c (2*25600) + xf,fcsum (2*6656) + F29 (14848)
    //                + halves/2: hsum16 3328 + emb16 9600 + h16 12800  = 105088
    const size_t PER_TREE = 105088;
    size_t avail = ws_size / sizeof(float);
    avail = (avail > WGT_FLOATS) ? (avail - WGT_FLOATS) : 0;
    int Bc = (int)(avail / PER_TREE);
    if (Bc > B) Bc = B;
    if (Bc < 1) Bc = 1;

    float* fbase = (float*)d_ws + WGT_FLOATS;
    size_t szH = (size_t)Bc * T_NODES * HID;
    size_t szP = (size_t)Bc * NPARL * HID;
    size_t szF = (size_t)Bc * 29 * HID;
    float* h     = fbase;
    float* c     = h     + szH;
    float* xf    = c     + szH;
    float* fcsum = xf    + szP;
    float* Fws   = fcsum + szP;
    _Float16* hsum16 = (_Float16*)(Fws + szF);
    _Float16* emb16  = hsum16 + szP;
    _Float16* h16    = emb16  + (size_t)Bc * T_NODES * DIN;

    dim3 blk(256);
    auto grd = [](int M, int ng) {
        unsigned nY = (unsigned)((M + BMR - 1) / BMR);
        nY = (nY + 7) & ~7u;                 // multiple of 8 for the XCD swizzle bijection
        return dim3((unsigned)(HID / ((ng == 3) ? 64 : 128)), nY);
    };

    // ---- weight transpose+convert (replayed each call; small) ----
    hipLaunchKernelGGL(transpose_cvt, dim3((DIN * 3 * HID + 255) / 256), blk, 0, stream,
                       W_iou, Wt_iou, DIN, 3 * HID);
    hipLaunchKernelGGL(transpose_cvt, dim3((HID * 3 * HID + 255) / 256), blk, 0, stream,
                       U_iou, Ut_iou, HID, 3 * HID);
    hipLaunchKernelGGL(transpose_cvt, dim3((DIN * HID + 255) / 256), blk, 0, stream,
                       W_f, Wt_f, DIN, HID);
    hipLaunchKernelGGL(transpose_cvt, dim3((HID * HID + 255) / 256), blk, 0, stream,
                       U_f, Ut_f, HID, HID);

    // Levels deep->root: children range, parent range, update range (locals)
    struct Lvl { int c0, cspan, p0, pspan, u0, uspan; };
    const Lvl L[3] = {
        {21, 29, 5, 8, 5, 8},
        { 5, 16, 1, 4, 1, 4},
        { 1,  4, 0, 1, 0, 1},
    };

    for (int g0 = 0; g0 < B; g0 += Bc) {
        const int bc = (B - g0 < Bc) ? (B - g0) : Bc;
        const float* embed_c = embed + (size_t)g0 * T_NODES * DIN;

        // chunk embed -> fp16 (19200 elems/tree, divisible by 8)
        {
            int n8 = bc * T_NODES * DIN / 8;
            hipLaunchKernelGGL(cvt_f32_f16, dim3((n8 + 255) / 256), blk, 0, stream,
                               embed_c, emb16, n8);
        }
        // Phase 0a: leaf update (zero child sums) for locals [13,50)
        {
            int M = bc * 37;
            hipLaunchKernelGGL((gemm_mfma<3, 0, false>), grd(M, 3), blk, 0, stream,
                emb16, DIN, (const _Float16*)nullptr, Wt_iou, (const _Float16*)nullptr,
                b_iou, (const float*)nullptr, (const float*)nullptr, (const float*)nullptr,
                h, c, h16, M, 13, 37);
        }
        // Phase 0b: xf = embed@W_f + b_f for parent locals [0,13)
        {
            int M = bc * NPARL;
            hipLaunchKernelGGL((gemm_mfma<1, 1, false>), grd(M, 1), blk, 0, stream,
                emb16, DIN, (const _Float16*)nullptr, Wt_f, (const _Float16*)nullptr,
                b_f, (const float*)nullptr, (const float*)nullptr, (const float*)nullptr,
                xf, (float*)nullptr, (_Float16*)nullptr, M, 0, NPARL);
        }
        for (int li = 0; li < 3; ++li) {
            const Lvl& v = L[li];
            int Mc = bc * v.cspan;
            hipLaunchKernelGGL((gemm_mfma<1, 2, false>), grd(Mc, 1), blk, 0, stream,
                h16, HID, (const _Float16*)nullptr, Ut_f, (const _Float16*)nullptr,
                (const float*)nullptr, xf, c, (const float*)nullptr,
                Fws, (float*)nullptr, (_Float16*)nullptr, Mc, v.c0, v.cspan);
            int Mp = bc * v.pspan;
            int tot = Mp * (HID / 4);
            hipLaunchKernelGGL(reduce_kernel, dim3((tot + 255) / 256), blk, 0, stream,
                h, Fws, hsum16, fcsum, Mp, v.p0, v.pspan, v.c0, v.cspan);
            int Mu = bc * v.uspan;
            hipLaunchKernelGGL((gemm_mfma<3, 0, true>), grd(Mu, 3), blk, 0, stream,
                emb16, DIN, hsum16, Wt_iou, Ut_iou, b_iou,
                (const float*)nullptr, (const float*)nullptr, fcsum,
                h, c, h16, Mu, v.u0, v.uspan);
        }
        // Readout for this chunk
        {
            int tot = bc * HID;
            hipLaunchKernelGGL(readout_kernel, dim3((tot + 255) / 256), blk, 0, stream,
                h, (float*)d_out, bc, g0, B);
        }
    }
}